// Round 1
// baseline (1611.593 us; speedup 1.0000x reference)
//
#include <hip/hip_runtime.h>
#include <hip/hip_bf16.h>

// Mamba block: B=2, L=512, d_model=1024, d_state=64, d_conv=4, expand=2 -> d_inner=2048
// Tokens: N_TOK = B*L = 1024
//
// Pipeline:
//  1) xz[1024][4096]  = x[1024][1024] @ in_proj_w[1024][4096]
//  2) xc[1024][2048]  = silu(causal_depthwise_conv(xs)), xs = xz[:, :2048]
//  3) xp[1024][129]   = xc @ x_proj_w[2048][129]   (B | C | dt_raw)
//  4) scan over L=512 (wave per (b,d)), fused dt=softplus, gating with silu(z)
//  5) out[1024][1024] = y @ out_proj_w[2048][1024]; state written directly

#define N_TOK   1024
#define SEQ_L   512
#define D_MODEL 1024
#define D_INNER 2048
#define D_STATE 64
#define D_XZ    4096
#define N_XP    129

// ---------------- generic f32 tiled GEMM: C[M,N] = A[M,K] @ W[K,N] -------------
template<int BM, int BN, int BK, int TM, int TN>
__global__ __launch_bounds__(256) void gemm_f32(
    const float* __restrict__ A, const float* __restrict__ W,
    float* __restrict__ C, int M, int N, int K) {
  __shared__ float As[BK][BM + 1];  // +1 pad: avoid 16-way bank conflict on transpose-write
  __shared__ float Ws[BK][BN];
  const int brow = blockIdx.y * BM;
  const int bcol = blockIdx.x * BN;
  const int tid = threadIdx.x;
  const int tr = tid / (BN / TN);
  const int tc = tid % (BN / TN);
  float acc[TM][TN] = {};
  for (int k0 = 0; k0 < K; k0 += BK) {
#pragma unroll
    for (int i = tid; i < BM * BK; i += 256) {
      int r = i / BK, c = i % BK;
      As[c][r] = A[(brow + r) * K + k0 + c];
    }
#pragma unroll
    for (int i = tid; i < BK * BN; i += 256) {
      int r = i / BN, c = i % BN;
      int col = bcol + c;
      Ws[r][c] = (col < N) ? W[(k0 + r) * N + col] : 0.f;
    }
    __syncthreads();
#pragma unroll
    for (int kk = 0; kk < BK; ++kk) {
      float av[TM], wv[TN];
#pragma unroll
      for (int m = 0; m < TM; ++m) av[m] = As[kk][tr * TM + m];
#pragma unroll
      for (int n = 0; n < TN; ++n) wv[n] = Ws[kk][tc * TN + n];
#pragma unroll
      for (int m = 0; m < TM; ++m)
#pragma unroll
        for (int n = 0; n < TN; ++n)
          acc[m][n] = fmaf(av[m], wv[n], acc[m][n]);
    }
    __syncthreads();
  }
#pragma unroll
  for (int m = 0; m < TM; ++m) {
    int row = brow + tr * TM + m;
#pragma unroll
    for (int n = 0; n < TN; ++n) {
      int col = bcol + tc * TN + n;
      if (col < N) C[row * N + col] = acc[m][n];
    }
  }
}

// ---------------- causal depthwise conv (K=4) + SiLU ---------------------------
__global__ __launch_bounds__(256) void conv_silu_kernel(
    const float* __restrict__ xz,   // [N_TOK][4096], xs = first 2048 cols
    const float* __restrict__ cw,   // [2048][4]
    const float* __restrict__ cb,   // [2048]
    float* __restrict__ xc) {       // [N_TOK][2048]
  int idx = blockIdx.x * blockDim.x + threadIdx.x;  // tok*2048 + c
  int c   = idx & (D_INNER - 1);
  int tok = idx >> 11;
  int l   = tok & (SEQ_L - 1);
  float acc = cb[c];
#pragma unroll
  for (int k = 0; k < 4; ++k) {
    int ll = l - 3 + k;
    if (ll >= 0) acc = fmaf(xz[(tok - 3 + k) * D_XZ + c], cw[c * 4 + k], acc);
  }
  float sig = 1.f / (1.f + __expf(-acc));
  xc[idx] = acc * sig;
}

// ---------------- selective scan: one wave per (b, d) --------------------------
__global__ __launch_bounds__(256) void scan_kernel(
    const float* __restrict__ xz,     // [N_TOK][4096] (z = cols 2048..4095)
    const float* __restrict__ xc,     // [N_TOK][2048]
    const float* __restrict__ xp,     // [N_TOK][129]  (B|C|dt_raw)
    const float* __restrict__ dt_w,   // [2048]
    const float* __restrict__ dt_b,   // [2048]
    const float* __restrict__ A_log,  // [2048][64]
    const float* __restrict__ Dvec,   // [2048]
    float* __restrict__ ybuf,         // [N_TOK][2048]
    float* __restrict__ state_out) {  // [B][2048][64]
  int wid  = (blockIdx.x * blockDim.x + threadIdx.x) >> 6;  // 0..4095
  int lane = threadIdx.x & 63;                              // = state index n
  int b = wid >> 11;
  int d = wid & (D_INNER - 1);
  float a  = -__expf(A_log[d * D_STATE + lane]);
  float dw = dt_w[d], db = dt_b[d], Dd = Dvec[d];
  float s = 0.f;
  const int base_tok = b * SEQ_L;
  for (int l = 0; l < SEQ_L; ++l) {
    int tok = base_tok + l;
    float dtr = xp[tok * N_XP + 128];
    float dt  = dtr * dw + db;
    dt = (dt > 20.f) ? dt : log1pf(__expf(dt));
    float xt = xc[tok * D_INNER + d];
    float Bn = xp[tok * N_XP + lane];
    float Cn = xp[tok * N_XP + 64 + lane];
    float dA = __expf(dt * a);
    s = fmaf(dA, s, dt * xt * Bn);
    float p = s * Cn;
#pragma unroll
    for (int off = 32; off >= 1; off >>= 1) p += __shfl_xor(p, off, 64);
    if (lane == 0) {
      float y = p + Dd * xt;
      float z = xz[tok * D_XZ + D_INNER + d];
      float sig = 1.f / (1.f + __expf(-z));
      ybuf[tok * D_INNER + d] = y * (z * sig);
    }
  }
  state_out[(b * D_INNER + d) * D_STATE + lane] = s;
}

extern "C" void kernel_launch(void* const* d_in, const int* in_sizes, int n_in,
                              void* d_out, int out_size, void* d_ws, size_t ws_size,
                              hipStream_t stream) {
  const float* x         = (const float*)d_in[0];
  const float* in_proj_w = (const float*)d_in[1];
  const float* conv_w    = (const float*)d_in[2];
  const float* conv_b    = (const float*)d_in[3];
  const float* x_proj_w  = (const float*)d_in[4];
  const float* dt_w      = (const float*)d_in[5];
  const float* dt_b      = (const float*)d_in[6];
  const float* A_log     = (const float*)d_in[7];
  const float* Dvec      = (const float*)d_in[8];
  const float* out_proj_w= (const float*)d_in[9];

  float* ws = (float*)d_ws;
  float* xz = ws;                          // 1024*4096 = 4194304
  float* xc = xz + (size_t)N_TOK * D_XZ;   // 1024*2048 = 2097152
  float* xp = xc + (size_t)N_TOK * D_INNER;// 1024*129  = 132096
  float* yb = xp + (size_t)N_TOK * N_XP;   // 1024*2048 = 2097152

  float* out       = (float*)d_out;               // 1024*1024
  float* state_out = out + (size_t)N_TOK * D_MODEL; // 2*2048*64

  dim3 blk(256);
  // 1) xz = x @ in_proj_w
  gemm_f32<64, 64, 16, 4, 4><<<dim3(D_XZ / 64, N_TOK / 64), blk, 0, stream>>>(
      x, in_proj_w, xz, N_TOK, D_XZ, D_MODEL);
  // 2) conv + silu
  conv_silu_kernel<<<(N_TOK * D_INNER) / 256, blk, 0, stream>>>(xz, conv_w, conv_b, xc);
  // 3) xp = xc @ x_proj_w  (N=129, guarded)
  gemm_f32<64, 64, 16, 4, 4><<<dim3((N_XP + 63) / 64, N_TOK / 64), blk, 0, stream>>>(
      xc, x_proj_w, xp, N_TOK, N_XP, D_INNER);
  // 4) scan (fused dt softplus + gating), writes ybuf and final state
  scan_kernel<<<(2 * D_INNER) * 64 / 256, blk, 0, stream>>>(
      xz, xc, xp, dt_w, dt_b, A_log, Dvec, yb, state_out);
  // 5) out = y @ out_proj_w
  gemm_f32<64, 64, 16, 4, 4><<<dim3(D_MODEL / 64, N_TOK / 64), blk, 0, stream>>>(
      yb, out_proj_w, out, N_TOK, D_MODEL, D_INNER);
}

// Round 2
// 449.911 us; speedup vs baseline: 3.5820x; 3.5820x over previous
//
#include <hip/hip_runtime.h>
#include <hip/hip_bf16.h>

// Mamba block on MI355X. B=2, L=512, d_model=1024, d_inner=2048, d_state=64, K=4.
// N_TOK = 1024.
// Pipeline:
//   w-prep: transpose+convert weights to bf16 [N][K]; convert x to bf16
//   gemm1:  xzf[1024][4096] = xb @ Wt1^T            (MFMA bf16)
//   conv :  xc = silu(causal depthwise conv(xs)), also bf16 copy xcb
//   gemm2:  xp[1024][129] = xcb @ Wt2^T             (MFMA bf16, N guarded)
//   pack :  u4[tok][d] = {dt(softplus), dt*x, D*x, silu(z)}
//   scan :  wave per (b,d), lane = n; writes ybb bf16 + final state (f32, d_out)
//   gemm3:  out[1024][1024] = ybb @ Wt3^T           (MFMA bf16, f32 out)

#define N_TOK   1024
#define SEQ_L   512
#define D_MODEL 1024
#define D_INNER 2048
#define D_STATE 64
#define D_XZ    4096
#define N_XP    129

typedef __attribute__((ext_vector_type(8))) short bf16x8;
typedef __attribute__((ext_vector_type(4))) float f32x4;

// ---------- transpose + f32->bf16 convert: dst[C][R] = bf16(src[R][C]) ----------
__global__ __launch_bounds__(256) void transpose_bf16(
    const float* __restrict__ src, __hip_bfloat16* __restrict__ dst, int R, int C) {
  __shared__ float t[64][65];
  int c0 = blockIdx.x * 64, r0 = blockIdx.y * 64;
  int tc = threadIdx.x & 63, tg = threadIdx.x >> 6;  // 4 row groups
#pragma unroll
  for (int i = 0; i < 16; ++i) {
    int r = r0 + tg + i * 4, c = c0 + tc;
    t[tg + i * 4][tc] = (r < R && c < C) ? src[(size_t)r * C + c] : 0.f;
  }
  __syncthreads();
#pragma unroll
  for (int i = 0; i < 16; ++i) {
    int c = c0 + tg + i * 4, r = r0 + tc;
    if (c < C && r < R) dst[(size_t)c * R + r] = __float2bfloat16(t[tc][tg + i * 4]);
  }
}

// ---------- plain f32 -> bf16 convert ----------
__global__ __launch_bounds__(256) void convert_bf16(
    const float* __restrict__ src, __hip_bfloat16* __restrict__ dst, int n) {
  int i = blockIdx.x * 256 + threadIdx.x;
  if (i < n) dst[i] = __float2bfloat16(src[i]);
}

// ---------- MFMA bf16 TN GEMM: C[M][N] = A[M][K] @ Bt[N][K]^T ----------
// tile 128x128, BK=32, 4 waves; each wave 64x64 (4x4 frags of 16x16x32)
template<int GUARD_N>
__global__ __launch_bounds__(256) void gemm_bf16_tn(
    const __hip_bfloat16* __restrict__ A, const __hip_bfloat16* __restrict__ Bt,
    float* __restrict__ C, int M, int N, int K) {
  __shared__ short As[128][40];  // rows padded to 80 B (16B-aligned)
  __shared__ short Bs[128][40];
  const int brow = blockIdx.y * 128, bcol = blockIdx.x * 128;
  const int tid = threadIdx.x;
  const int lane = tid & 63, wave = tid >> 6;
  const int wm = wave >> 1, wn = wave & 1;
  const int l15 = lane & 15, lk = lane >> 4;
  f32x4 acc[4][4] = {};
  for (int k0 = 0; k0 < K; k0 += 32) {
#pragma unroll
    for (int i = 0; i < 2; ++i) {
      int v = tid + i * 256;         // 0..511 vector slots (8 bf16 each)
      int r = v >> 2, kc = (v & 3) * 8;
      *(bf16x8*)((char*)&As[0][0] + r * 80 + kc * 2) =
          *(const bf16x8*)&A[(size_t)(brow + r) * K + k0 + kc];
      bf16x8 bv = {};
      if (!GUARD_N || (bcol + r) < N)
        bv = *(const bf16x8*)&Bt[(size_t)(bcol + r) * K + k0 + kc];
      *(bf16x8*)((char*)&Bs[0][0] + r * 80 + kc * 2) = bv;
    }
    __syncthreads();
    bf16x8 af[4], bfr[4];
#pragma unroll
    for (int m = 0; m < 4; ++m)
      af[m] = *(const bf16x8*)((const char*)&As[0][0] + (wm * 64 + m * 16 + l15) * 80 + lk * 16);
#pragma unroll
    for (int n = 0; n < 4; ++n)
      bfr[n] = *(const bf16x8*)((const char*)&Bs[0][0] + (wn * 64 + n * 16 + l15) * 80 + lk * 16);
#pragma unroll
    for (int m = 0; m < 4; ++m)
#pragma unroll
      for (int n = 0; n < 4; ++n)
        acc[m][n] = __builtin_amdgcn_mfma_f32_16x16x32_bf16(af[m], bfr[n], acc[m][n], 0, 0, 0);
    __syncthreads();
  }
  // C/D layout (verified m89): col = lane&15, row = (lane>>4)*4 + reg
#pragma unroll
  for (int m = 0; m < 4; ++m) {
    int row = brow + wm * 64 + m * 16 + lk * 4;
#pragma unroll
    for (int n = 0; n < 4; ++n) {
      int col = bcol + wn * 64 + n * 16 + l15;
      if (!GUARD_N || col < N) {
#pragma unroll
        for (int r = 0; r < 4; ++r)
          C[(size_t)(row + r) * N + col] = acc[m][n][r];
      }
    }
  }
}

// ---------- causal depthwise conv (K=4) + SiLU; writes f32 + bf16 ----------
__global__ __launch_bounds__(256) void conv_silu_kernel(
    const float* __restrict__ xz, const float* __restrict__ cw,
    const float* __restrict__ cb, float* __restrict__ xc,
    __hip_bfloat16* __restrict__ xcb) {
  int idx = blockIdx.x * 256 + threadIdx.x;  // tok*2048 + c
  int c = idx & (D_INNER - 1);
  int tok = idx >> 11;
  int l = tok & (SEQ_L - 1);
  float acc = cb[c];
#pragma unroll
  for (int k = 0; k < 4; ++k) {
    int ll = l - 3 + k;
    if (ll >= 0) acc = fmaf(xz[(size_t)(tok - 3 + k) * D_XZ + c], cw[c * 4 + k], acc);
  }
  float v = acc / (1.f + __expf(-acc));
  xc[idx] = v;
  xcb[idx] = __float2bfloat16(v);
}

// ---------- pack per-(tok,d) uniforms: {dt, dt*x, D*x, silu(z)} ----------
__global__ __launch_bounds__(256) void pack_kernel(
    const float* __restrict__ xz, const float* __restrict__ xc,
    const float* __restrict__ xp, const float* __restrict__ dt_w,
    const float* __restrict__ dt_b, const float* __restrict__ Dv,
    float4* __restrict__ u4) {
  int idx = blockIdx.x * 256 + threadIdx.x;  // tok*2048 + d
  int d = idx & (D_INNER - 1);
  int tok = idx >> 11;
  float dtr = xp[tok * N_XP + 128];
  float dt = dtr * dt_w[d] + dt_b[d];
  dt = (dt > 20.f) ? dt : log1pf(__expf(dt));
  float xt = xc[idx];
  float z = xz[(size_t)tok * D_XZ + D_INNER + d];
  float g = z / (1.f + __expf(-z));
  u4[idx] = make_float4(dt, dt * xt, Dv[d] * xt, g);
}

// ---------- selective scan: wave per (b,d), lane = n; unroll 4 ----------
__global__ __launch_bounds__(256) void scan_kernel(
    const float* __restrict__ xp, const float4* __restrict__ u4,
    const float* __restrict__ A_log, __hip_bfloat16* __restrict__ ybb,
    float* __restrict__ state_out) {
  int wid = (blockIdx.x * 256 + threadIdx.x) >> 6;  // 0..4095
  int lane = threadIdx.x & 63;                       // state index n
  int b = wid >> 11, d = wid & (D_INNER - 1);
  float a = -__expf(A_log[d * D_STATE + lane]);
  float s = 0.f;
  const int tok0 = b * SEQ_L;
  const float* xpt = xp + (size_t)tok0 * N_XP;
  const float4* ut = u4 + (size_t)tok0 * D_INNER + d;
  for (int l = 0; l < SEQ_L; l += 4) {
    float p[4], yc[4], gg[4];
#pragma unroll
    for (int j = 0; j < 4; ++j) {
      float4 u = ut[(size_t)(l + j) * D_INNER];     // uniform b128 broadcast
      float Bn = xpt[(l + j) * N_XP + lane];
      float Cn = xpt[(l + j) * N_XP + 64 + lane];
      float dA = __expf(u.x * a);
      s = fmaf(dA, s, u.y * Bn);
      p[j] = s * Cn;
      yc[j] = u.z; gg[j] = u.w;
    }
#pragma unroll
    for (int off = 32; off >= 1; off >>= 1) {
#pragma unroll
      for (int j = 0; j < 4; ++j) p[j] += __shfl_xor(p[j], off, 64);
    }
    if (lane == 0) {
#pragma unroll
      for (int j = 0; j < 4; ++j)
        ybb[(size_t)(tok0 + l + j) * D_INNER + d] =
            __float2bfloat16((p[j] + yc[j]) * gg[j]);
    }
  }
  state_out[(size_t)wid * D_STATE + lane] = s;
}

extern "C" void kernel_launch(void* const* d_in, const int* in_sizes, int n_in,
                              void* d_out, int out_size, void* d_ws, size_t ws_size,
                              hipStream_t stream) {
  const float* x         = (const float*)d_in[0];
  const float* in_proj_w = (const float*)d_in[1];
  const float* conv_w    = (const float*)d_in[2];
  const float* conv_b    = (const float*)d_in[3];
  const float* x_proj_w  = (const float*)d_in[4];
  const float* dt_w      = (const float*)d_in[5];
  const float* dt_b      = (const float*)d_in[6];
  const float* A_log     = (const float*)d_in[7];
  const float* Dvec      = (const float*)d_in[8];
  const float* out_proj_w= (const float*)d_in[9];

  char* w = (char*)d_ws;
  __hip_bfloat16* Wt1 = (__hip_bfloat16*)w; w += (size_t)D_XZ * D_MODEL * 2;      // 8 MB
  __hip_bfloat16* Wt2 = (__hip_bfloat16*)w; w += (size_t)N_XP * D_INNER * 2;      // 516 KB
  __hip_bfloat16* Wt3 = (__hip_bfloat16*)w; w += (size_t)D_MODEL * D_INNER * 2;   // 4 MB
  __hip_bfloat16* xb  = (__hip_bfloat16*)w; w += (size_t)N_TOK * D_MODEL * 2;     // 2 MB
  float*          xzf = (float*)w;          w += (size_t)N_TOK * D_XZ * 4;        // 16 MB
  float*          xc  = (float*)w;          w += (size_t)N_TOK * D_INNER * 4;     // 8 MB
  __hip_bfloat16* xcb = (__hip_bfloat16*)w; w += (size_t)N_TOK * D_INNER * 2;     // 4 MB
  float*          xp  = (float*)w;          w += (size_t)N_TOK * N_XP * 4;        // 516 KB
  float4*         u4  = (float4*)w;         w += (size_t)N_TOK * D_INNER * 16;    // 32 MB
  __hip_bfloat16* ybb = (__hip_bfloat16*)w; w += (size_t)N_TOK * D_INNER * 2;     // 4 MB

  float* out       = (float*)d_out;                    // 1024*1024
  float* state_out = out + (size_t)N_TOK * D_MODEL;    // 2*2048*64

  dim3 blk(256);
  // weight prep
  transpose_bf16<<<dim3(D_XZ / 64, D_MODEL / 64), blk, 0, stream>>>(in_proj_w, Wt1, D_MODEL, D_XZ);
  transpose_bf16<<<dim3((N_XP + 63) / 64, D_INNER / 64), blk, 0, stream>>>(x_proj_w, Wt2, D_INNER, N_XP);
  transpose_bf16<<<dim3(D_MODEL / 64, D_INNER / 64), blk, 0, stream>>>(out_proj_w, Wt3, D_INNER, D_MODEL);
  convert_bf16<<<(N_TOK * D_MODEL) / 256, blk, 0, stream>>>(x, xb, N_TOK * D_MODEL);
  // 1) xz = x @ in_proj_w
  gemm_bf16_tn<0><<<dim3(D_XZ / 128, N_TOK / 128), blk, 0, stream>>>(xb, Wt1, xzf, N_TOK, D_XZ, D_MODEL);
  // 2) conv + silu
  conv_silu_kernel<<<(N_TOK * D_INNER) / 256, blk, 0, stream>>>(xzf, conv_w, conv_b, xc, xcb);
  // 3) xp = xc @ x_proj_w (N=129 guarded)
  gemm_bf16_tn<1><<<dim3((N_XP + 127) / 128, N_TOK / 128), blk, 0, stream>>>(xcb, Wt2, xp, N_TOK, N_XP, D_INNER);
  // 4) pack uniforms
  pack_kernel<<<(N_TOK * D_INNER) / 256, blk, 0, stream>>>(xzf, xc, xp, dt_w, dt_b, Dvec, u4);
  // 5) scan
  scan_kernel<<<(2 * D_INNER * 64) / 256, blk, 0, stream>>>(xp, u4, A_log, ybb, state_out);
  // 6) out = y @ out_proj_w
  gemm_bf16_tn<0><<<dim3(D_MODEL / 128, N_TOK / 128), blk, 0, stream>>>(ybb, Wt3, out, N_TOK, D_MODEL, D_INNER);
}

// Round 3
// 388.491 us; speedup vs baseline: 4.1483x; 1.1581x over previous
//
#include <hip/hip_runtime.h>
#include <hip/hip_bf16.h>

// Mamba block on MI355X. B=2, L=512, d_model=1024, d_inner=2048, d_state=64, K=4.
// Pipeline:
//   w-prep: transpose+convert weights to bf16 [N][K]; convert x to bf16
//   gemm1:  xzf[1024][4096] = xb @ Wt1^T              (MFMA bf16)
//   conv :  xc = silu(causal depthwise conv(xs)) (+bf16 copy)
//   gemm2:  split-K x16 partials of xc @ x_proj_w -> reduce -> xp[1024][129]
//   pack :  u4[tok][d] = {dt, dt*x, D*x, silu(z)}; bc[tok][n] = {B,C}
//   scan :  wave per (b,d), lane=n, DPP wave-sum (no DS ops); ybb bf16 + state
//   gemm3:  out[1024][1024] = ybb @ Wt3^T             (MFMA bf16, f32 out)

#define N_TOK   1024
#define SEQ_L   512
#define D_MODEL 1024
#define D_INNER 2048
#define D_STATE 64
#define D_XZ    4096
#define N_XP    129

typedef __attribute__((ext_vector_type(8))) short bf16x8;
typedef __attribute__((ext_vector_type(4))) float f32x4;

// ---------- transpose + f32->bf16 convert: dst[C][R] = bf16(src[R][C]) ----------
__global__ __launch_bounds__(256) void transpose_bf16(
    const float* __restrict__ src, __hip_bfloat16* __restrict__ dst, int R, int C) {
  __shared__ float t[64][65];
  int c0 = blockIdx.x * 64, r0 = blockIdx.y * 64;
  int tc = threadIdx.x & 63, tg = threadIdx.x >> 6;
#pragma unroll
  for (int i = 0; i < 16; ++i) {
    int r = r0 + tg + i * 4, c = c0 + tc;
    t[tg + i * 4][tc] = (r < R && c < C) ? src[(size_t)r * C + c] : 0.f;
  }
  __syncthreads();
#pragma unroll
  for (int i = 0; i < 16; ++i) {
    int c = c0 + tg + i * 4, r = r0 + tc;
    if (c < C && r < R) dst[(size_t)c * R + r] = __float2bfloat16(t[tc][tg + i * 4]);
  }
}

__global__ __launch_bounds__(256) void convert_bf16(
    const float* __restrict__ src, __hip_bfloat16* __restrict__ dst, int n) {
  int i = blockIdx.x * 256 + threadIdx.x;
  if (i < n) dst[i] = __float2bfloat16(src[i]);
}

// ---------- MFMA bf16 TN GEMM: C[M][N] = A[M][K] @ Bt[N][K]^T ----------
template<int GUARD_N>
__global__ __launch_bounds__(256) void gemm_bf16_tn(
    const __hip_bfloat16* __restrict__ A, const __hip_bfloat16* __restrict__ Bt,
    float* __restrict__ C, int M, int N, int K) {
  __shared__ short As[128][40];  // rows padded to 80 B
  __shared__ short Bs[128][40];
  const int brow = blockIdx.y * 128, bcol = blockIdx.x * 128;
  const int tid = threadIdx.x;
  const int lane = tid & 63, wave = tid >> 6;
  const int wm = wave >> 1, wn = wave & 1;
  const int l15 = lane & 15, lk = lane >> 4;
  f32x4 acc[4][4] = {};
  for (int k0 = 0; k0 < K; k0 += 32) {
#pragma unroll
    for (int i = 0; i < 2; ++i) {
      int v = tid + i * 256;
      int r = v >> 2, kc = (v & 3) * 8;
      *(bf16x8*)((char*)&As[0][0] + r * 80 + kc * 2) =
          *(const bf16x8*)&A[(size_t)(brow + r) * K + k0 + kc];
      bf16x8 bv = {};
      if (!GUARD_N || (bcol + r) < N)
        bv = *(const bf16x8*)&Bt[(size_t)(bcol + r) * K + k0 + kc];
      *(bf16x8*)((char*)&Bs[0][0] + r * 80 + kc * 2) = bv;
    }
    __syncthreads();
    bf16x8 af[4], bfr[4];
#pragma unroll
    for (int m = 0; m < 4; ++m)
      af[m] = *(const bf16x8*)((const char*)&As[0][0] + (wm * 64 + m * 16 + l15) * 80 + lk * 16);
#pragma unroll
    for (int n = 0; n < 4; ++n)
      bfr[n] = *(const bf16x8*)((const char*)&Bs[0][0] + (wn * 64 + n * 16 + l15) * 80 + lk * 16);
#pragma unroll
    for (int m = 0; m < 4; ++m)
#pragma unroll
      for (int n = 0; n < 4; ++n)
        acc[m][n] = __builtin_amdgcn_mfma_f32_16x16x32_bf16(af[m], bfr[n], acc[m][n], 0, 0, 0);
    __syncthreads();
  }
#pragma unroll
  for (int m = 0; m < 4; ++m) {
    int row = brow + wm * 64 + m * 16 + lk * 4;
#pragma unroll
    for (int n = 0; n < 4; ++n) {
      int col = bcol + wn * 64 + n * 16 + l15;
      if (!GUARD_N || col < N) {
#pragma unroll
        for (int r = 0; r < 4; ++r)
          C[(size_t)(row + r) * N + col] = acc[m][n][r];
      }
    }
  }
}

// ---------- gemm2 split-K: P[z][M][129] partials, K-chunk 128 ----------
__global__ __launch_bounds__(256) void gemm2_splitk(
    const __hip_bfloat16* __restrict__ A, const __hip_bfloat16* __restrict__ Bt,
    float* __restrict__ P, int M, int N, int K) {
  __shared__ short As[128][40];
  __shared__ short Bs[128][40];
  const int brow = blockIdx.y * 128, bcol = blockIdx.x * 128;
  const int kbase = blockIdx.z * 128;
  const int tid = threadIdx.x;
  const int lane = tid & 63, wave = tid >> 6;
  const int wm = wave >> 1, wn = wave & 1;
  const int l15 = lane & 15, lk = lane >> 4;
  f32x4 acc[4][4] = {};
  for (int k0 = kbase; k0 < kbase + 128; k0 += 32) {
#pragma unroll
    for (int i = 0; i < 2; ++i) {
      int v = tid + i * 256;
      int r = v >> 2, kc = (v & 3) * 8;
      *(bf16x8*)((char*)&As[0][0] + r * 80 + kc * 2) =
          *(const bf16x8*)&A[(size_t)(brow + r) * K + k0 + kc];
      bf16x8 bv = {};
      if ((bcol + r) < N)
        bv = *(const bf16x8*)&Bt[(size_t)(bcol + r) * K + k0 + kc];
      *(bf16x8*)((char*)&Bs[0][0] + r * 80 + kc * 2) = bv;
    }
    __syncthreads();
    bf16x8 af[4], bfr[4];
#pragma unroll
    for (int m = 0; m < 4; ++m)
      af[m] = *(const bf16x8*)((const char*)&As[0][0] + (wm * 64 + m * 16 + l15) * 80 + lk * 16);
#pragma unroll
    for (int n = 0; n < 4; ++n)
      bfr[n] = *(const bf16x8*)((const char*)&Bs[0][0] + (wn * 64 + n * 16 + l15) * 80 + lk * 16);
#pragma unroll
    for (int m = 0; m < 4; ++m)
#pragma unroll
      for (int n = 0; n < 4; ++n)
        acc[m][n] = __builtin_amdgcn_mfma_f32_16x16x32_bf16(af[m], bfr[n], acc[m][n], 0, 0, 0);
    __syncthreads();
  }
  float* Pz = P + (size_t)blockIdx.z * M * N;
#pragma unroll
  for (int m = 0; m < 4; ++m) {
    int row = brow + wm * 64 + m * 16 + lk * 4;
#pragma unroll
    for (int n = 0; n < 4; ++n) {
      int col = bcol + wn * 64 + n * 16 + l15;
      if (col < N) {
#pragma unroll
        for (int r = 0; r < 4; ++r)
          Pz[(size_t)(row + r) * N + col] = acc[m][n][r];
      }
    }
  }
}

__global__ __launch_bounds__(256) void reduce_xp(
    const float* __restrict__ P, float* __restrict__ xp, int n) {
  int i = blockIdx.x * 256 + threadIdx.x;
  if (i >= n) return;
  float s = 0.f;
#pragma unroll
  for (int z = 0; z < 16; ++z) s += P[(size_t)z * n + i];
  xp[i] = s;
}

// ---------- causal depthwise conv (K=4) + SiLU ----------
__global__ __launch_bounds__(256) void conv_silu_kernel(
    const float* __restrict__ xz, const float* __restrict__ cw,
    const float* __restrict__ cb, float* __restrict__ xc,
    __hip_bfloat16* __restrict__ xcb) {
  int idx = blockIdx.x * 256 + threadIdx.x;
  int c = idx & (D_INNER - 1);
  int tok = idx >> 11;
  int l = tok & (SEQ_L - 1);
  float acc = cb[c];
#pragma unroll
  for (int k = 0; k < 4; ++k) {
    int ll = l - 3 + k;
    if (ll >= 0) acc = fmaf(xz[(size_t)(tok - 3 + k) * D_XZ + c], cw[c * 4 + k], acc);
  }
  float v = acc / (1.f + __expf(-acc));
  xc[idx] = v;
  xcb[idx] = __float2bfloat16(v);
}

// ---------- pack: u4 = {dt, dt*x, D*x, silu(z)}; bc = {B, C} ----------
__global__ __launch_bounds__(256) void pack_kernel(
    const float* __restrict__ xz, const float* __restrict__ xc,
    const float* __restrict__ xp, const float* __restrict__ dt_w,
    const float* __restrict__ dt_b, const float* __restrict__ Dv,
    float4* __restrict__ u4, float2* __restrict__ bc) {
  int idx = blockIdx.x * 256 + threadIdx.x;
  int d = idx & (D_INNER - 1);
  int tok = idx >> 11;
  float dtr = xp[tok * N_XP + 128];
  float dt = dtr * dt_w[d] + dt_b[d];
  dt = (dt > 20.f) ? dt : log1pf(__expf(dt));
  float xt = xc[idx];
  float z = xz[(size_t)tok * D_XZ + D_INNER + d];
  float g = z / (1.f + __expf(-z));
  u4[idx] = make_float4(dt, dt * xt, Dv[d] * xt, g);
  if (d < D_STATE)
    bc[tok * D_STATE + d] =
        make_float2(xp[tok * N_XP + d], xp[tok * N_XP + D_STATE + d]);
}

// ---------- DPP wave-64 sum: result in lane 63, pure VALU ----------
template<int CTRL>
__device__ __forceinline__ float dppadd(float v) {
  int t = __builtin_amdgcn_update_dpp(0, __float_as_int(v), CTRL, 0xF, 0xF, true);
  return v + __int_as_float(t);
}
__device__ __forceinline__ float wave_sum64(float v) {
  v = dppadd<0x111>(v);  // row_shr:1
  v = dppadd<0x112>(v);  // row_shr:2
  v = dppadd<0x114>(v);  // row_shr:4
  v = dppadd<0x118>(v);  // row_shr:8
  v = dppadd<0x142>(v);  // row_bcast:15
  v = dppadd<0x143>(v);  // row_bcast:31
  return v;
}

// ---------- selective scan: wave per (b,d), lane = n ----------
__global__ __launch_bounds__(256) void scan_kernel(
    const float2* __restrict__ bc, const float4* __restrict__ u4,
    const float* __restrict__ A_log, __hip_bfloat16* __restrict__ ybb,
    float* __restrict__ state_out) {
  int wid = (blockIdx.x * 256 + threadIdx.x) >> 6;
  int lane = threadIdx.x & 63;
  int b = wid >> 11, d = wid & (D_INNER - 1);
  float a = -__expf(A_log[d * D_STATE + lane]);
  float s = 0.f;
  const int tok0 = b * SEQ_L;
  const float4* ut = u4 + (size_t)tok0 * D_INNER + d;
  const float2* bct = bc + (size_t)tok0 * D_STATE + lane;
  __hip_bfloat16* yo = ybb + (size_t)tok0 * D_INNER + d;
  for (int l = 0; l < SEQ_L; l += 8) {
    float4 u[8];
    float2 bcv[8];
#pragma unroll
    for (int j = 0; j < 8; ++j) {
      u[j] = ut[(size_t)j * D_INNER];
      bcv[j] = bct[(size_t)j * D_STATE];
    }
#pragma unroll
    for (int j = 0; j < 8; ++j) {
      float dA = __expf(u[j].x * a);
      s = fmaf(dA, s, u[j].y * bcv[j].x);
      float p = wave_sum64(s * bcv[j].y);
      if (lane == 63)
        yo[(size_t)j * D_INNER] = __float2bfloat16((p + u[j].z) * u[j].w);
    }
    ut += (size_t)8 * D_INNER;
    bct += (size_t)8 * D_STATE;
    yo += (size_t)8 * D_INNER;
  }
  state_out[(size_t)wid * D_STATE + lane] = s;
}

extern "C" void kernel_launch(void* const* d_in, const int* in_sizes, int n_in,
                              void* d_out, int out_size, void* d_ws, size_t ws_size,
                              hipStream_t stream) {
  const float* x         = (const float*)d_in[0];
  const float* in_proj_w = (const float*)d_in[1];
  const float* conv_w    = (const float*)d_in[2];
  const float* conv_b    = (const float*)d_in[3];
  const float* x_proj_w  = (const float*)d_in[4];
  const float* dt_w      = (const float*)d_in[5];
  const float* dt_b      = (const float*)d_in[6];
  const float* A_log     = (const float*)d_in[7];
  const float* Dvec      = (const float*)d_in[8];
  const float* out_proj_w= (const float*)d_in[9];

  char* w = (char*)d_ws;
  __hip_bfloat16* Wt1 = (__hip_bfloat16*)w; w += (size_t)D_XZ * D_MODEL * 2;      // 8 MB
  __hip_bfloat16* Wt2 = (__hip_bfloat16*)w; w += (size_t)N_XP * D_INNER * 2;      // 516 KB
  __hip_bfloat16* Wt3 = (__hip_bfloat16*)w; w += (size_t)D_MODEL * D_INNER * 2;   // 4 MB
  __hip_bfloat16* xb  = (__hip_bfloat16*)w; w += (size_t)N_TOK * D_MODEL * 2;     // 2 MB
  float*          xzf = (float*)w;          w += (size_t)N_TOK * D_XZ * 4;        // 16 MB
  float*          xc  = (float*)w;          w += (size_t)N_TOK * D_INNER * 4;     // 8 MB
  __hip_bfloat16* xcb = (__hip_bfloat16*)w; w += (size_t)N_TOK * D_INNER * 2;     // 4 MB
  float*          xp  = (float*)w;          w += (size_t)N_TOK * N_XP * 4;        // 516 KB
  float4*         u4  = (float4*)w;         w += (size_t)N_TOK * D_INNER * 16;    // 32 MB
  __hip_bfloat16* ybb = (__hip_bfloat16*)w; w += (size_t)N_TOK * D_INNER * 2;     // 4 MB
  float2*         bc  = (float2*)w;         w += (size_t)N_TOK * D_STATE * 8;     // 512 KB
  // split-K partials alias u4's region (u4 written later by pack, after reduce)
  float* P = (float*)u4;  // 16 * 1024*129 * 4 B = 8.45 MB < 32 MB

  float* out       = (float*)d_out;
  float* state_out = out + (size_t)N_TOK * D_MODEL;

  dim3 blk(256);
  transpose_bf16<<<dim3(D_XZ / 64, D_MODEL / 64), blk, 0, stream>>>(in_proj_w, Wt1, D_MODEL, D_XZ);
  transpose_bf16<<<dim3((N_XP + 63) / 64, D_INNER / 64), blk, 0, stream>>>(x_proj_w, Wt2, D_INNER, N_XP);
  transpose_bf16<<<dim3(D_MODEL / 64, D_INNER / 64), blk, 0, stream>>>(out_proj_w, Wt3, D_INNER, D_MODEL);
  convert_bf16<<<(N_TOK * D_MODEL) / 256, blk, 0, stream>>>(x, xb, N_TOK * D_MODEL);
  // 1) xz = x @ in_proj_w
  gemm_bf16_tn<0><<<dim3(D_XZ / 128, N_TOK / 128), blk, 0, stream>>>(xb, Wt1, xzf, N_TOK, D_XZ, D_MODEL);
  // 2) conv + silu
  conv_silu_kernel<<<(N_TOK * D_INNER) / 256, blk, 0, stream>>>(xzf, conv_w, conv_b, xc, xcb);
  // 3) xp = xc @ x_proj_w : split-K x16 + reduce
  gemm2_splitk<<<dim3((N_XP + 127) / 128, N_TOK / 128, 16), blk, 0, stream>>>(xcb, Wt2, P, N_TOK, N_XP, D_INNER);
  reduce_xp<<<(N_TOK * N_XP + 255) / 256, blk, 0, stream>>>(P, xp, N_TOK * N_XP);
  // 4) pack uniforms (+ bc pairs)
  pack_kernel<<<(N_TOK * D_INNER) / 256, blk, 0, stream>>>(xzf, xc, xp, dt_w, dt_b, Dvec, u4, bc);
  // 5) scan (DPP reduce)
  scan_kernel<<<(2 * D_INNER * 64) / 256, blk, 0, stream>>>(bc, u4, A_log, ybb, state_out);
  // 6) out = y @ out_proj_w
  gemm_bf16_tn<0><<<dim3(D_MODEL / 128, N_TOK / 128), blk, 0, stream>>>(ybb, Wt3, out, N_TOK, D_MODEL, D_INNER);
}

// Round 4
// 364.414 us; speedup vs baseline: 4.4224x; 1.0661x over previous
//
#include <hip/hip_runtime.h>
#include <hip/hip_bf16.h>

// Mamba block on MI355X. B=2, L=512, d_model=1024, d_inner=2048, d_state=64, K=4.
// Pipeline:
//   transpose x3 : weights -> bf16 [N][K]
//   gemm1 : xzf[1024][4096] = x(f32, cvt in stage) @ Wt1^T   (MFMA bf16, f32 out)
//   conv  : xc = silu(causal depthwise conv(xs)) f32 + bf16 copy
//   gemm2 : split-K x16 partials of xcb @ Wt2^T -> P
//   reduce_bc : P -> bcT[n][tok] (bf16x2 {B,C}) + dtr[tok]
//   pack  : uaT[d][tok] = {dt, dt*x} f32x2 ; ugT[d][tok] = bf16x2 {D*x, silu(z)}
//   scan  : wave per (b,d), lane=n; transposed streaming + 2-deep pipeline + DPP
//   gemm3 : out[1024][1024] = ybb @ Wt3^T   (MFMA bf16, f32 out)

#define N_TOK   1024
#define SEQ_L   512
#define D_MODEL 1024
#define D_INNER 2048
#define D_STATE 64
#define D_XZ    4096
#define N_XP    129

typedef __attribute__((ext_vector_type(8))) short bf16x8;
typedef __attribute__((ext_vector_type(4))) float f32x4;

__device__ __forceinline__ unsigned short f2bf(float f) {
  __hip_bfloat16 h = __float2bfloat16(f);
  return *reinterpret_cast<unsigned short*>(&h);
}
__device__ __forceinline__ float bf16lo(unsigned int u) { return __uint_as_float(u << 16); }
__device__ __forceinline__ float bf16hi(unsigned int u) { return __uint_as_float(u & 0xffff0000u); }

// ---------- transpose + f32->bf16 convert: dst[C][R] = bf16(src[R][C]) ----------
__global__ __launch_bounds__(256) void transpose_bf16(
    const float* __restrict__ src, __hip_bfloat16* __restrict__ dst, int R, int C) {
  __shared__ float t[64][65];
  int c0 = blockIdx.x * 64, r0 = blockIdx.y * 64;
  int tc = threadIdx.x & 63, tg = threadIdx.x >> 6;
#pragma unroll
  for (int i = 0; i < 16; ++i) {
    int r = r0 + tg + i * 4, c = c0 + tc;
    t[tg + i * 4][tc] = (r < R && c < C) ? src[(size_t)r * C + c] : 0.f;
  }
  __syncthreads();
#pragma unroll
  for (int i = 0; i < 16; ++i) {
    int c = c0 + tg + i * 4, r = r0 + tc;
    if (c < C && r < R) dst[(size_t)c * R + r] = __float2bfloat16(t[tc][tg + i * 4]);
  }
}

// ---------- MFMA bf16 TN GEMM: C[M][N] = A[M][K] @ Bt[N][K]^T ----------
// A_F32: stage A from f32 with in-register cvt. Tile 128x128, BK=32, 4 waves.
template<int A_F32>
__global__ __launch_bounds__(256) void gemm_bf16_tn(
    const void* __restrict__ Av, const __hip_bfloat16* __restrict__ Bt,
    float* __restrict__ C, int M, int N, int K) {
  __shared__ short As[128][40];  // rows padded to 80 B
  __shared__ short Bs[128][40];
  const int brow = blockIdx.y * 128, bcol = blockIdx.x * 128;
  const int tid = threadIdx.x;
  const int lane = tid & 63, wave = tid >> 6;
  const int wm = wave >> 1, wn = wave & 1;
  const int l15 = lane & 15, lk = lane >> 4;
  f32x4 acc[4][4] = {};
  for (int k0 = 0; k0 < K; k0 += 32) {
#pragma unroll
    for (int i = 0; i < 2; ++i) {
      int v = tid + i * 256;
      int r = v >> 2, kc = (v & 3) * 8;
      if (A_F32) {
        const float* Af = (const float*)Av;
        float4 f0 = *(const float4*)&Af[(size_t)(brow + r) * K + k0 + kc];
        float4 f1 = *(const float4*)&Af[(size_t)(brow + r) * K + k0 + kc + 4];
        bf16x8 h;
        h[0] = (short)f2bf(f0.x); h[1] = (short)f2bf(f0.y);
        h[2] = (short)f2bf(f0.z); h[3] = (short)f2bf(f0.w);
        h[4] = (short)f2bf(f1.x); h[5] = (short)f2bf(f1.y);
        h[6] = (short)f2bf(f1.z); h[7] = (short)f2bf(f1.w);
        *(bf16x8*)((char*)&As[0][0] + r * 80 + kc * 2) = h;
      } else {
        const __hip_bfloat16* Ab = (const __hip_bfloat16*)Av;
        *(bf16x8*)((char*)&As[0][0] + r * 80 + kc * 2) =
            *(const bf16x8*)&Ab[(size_t)(brow + r) * K + k0 + kc];
      }
      *(bf16x8*)((char*)&Bs[0][0] + r * 80 + kc * 2) =
          *(const bf16x8*)&Bt[(size_t)(bcol + r) * K + k0 + kc];
    }
    __syncthreads();
    bf16x8 af[4], bfr[4];
#pragma unroll
    for (int m = 0; m < 4; ++m)
      af[m] = *(const bf16x8*)((const char*)&As[0][0] + (wm * 64 + m * 16 + l15) * 80 + lk * 16);
#pragma unroll
    for (int n = 0; n < 4; ++n)
      bfr[n] = *(const bf16x8*)((const char*)&Bs[0][0] + (wn * 64 + n * 16 + l15) * 80 + lk * 16);
#pragma unroll
    for (int m = 0; m < 4; ++m)
#pragma unroll
      for (int n = 0; n < 4; ++n)
        acc[m][n] = __builtin_amdgcn_mfma_f32_16x16x32_bf16(af[m], bfr[n], acc[m][n], 0, 0, 0);
    __syncthreads();
  }
#pragma unroll
  for (int m = 0; m < 4; ++m) {
    int row = brow + wm * 64 + m * 16 + lk * 4;
#pragma unroll
    for (int n = 0; n < 4; ++n) {
      int col = bcol + wn * 64 + n * 16 + l15;
#pragma unroll
      for (int r = 0; r < 4; ++r)
        C[(size_t)(row + r) * N + col] = acc[m][n][r];
    }
  }
}

// ---------- gemm2 split-K: P[z][M][129] partials, K-chunk 128 ----------
__global__ __launch_bounds__(256) void gemm2_splitk(
    const __hip_bfloat16* __restrict__ A, const __hip_bfloat16* __restrict__ Bt,
    float* __restrict__ P, int M, int N, int K) {
  __shared__ short As[128][40];
  __shared__ short Bs[128][40];
  const int brow = blockIdx.y * 128, bcol = blockIdx.x * 128;
  const int kbase = blockIdx.z * 128;
  const int tid = threadIdx.x;
  const int lane = tid & 63, wave = tid >> 6;
  const int wm = wave >> 1, wn = wave & 1;
  const int l15 = lane & 15, lk = lane >> 4;
  f32x4 acc[4][4] = {};
  for (int k0 = kbase; k0 < kbase + 128; k0 += 32) {
#pragma unroll
    for (int i = 0; i < 2; ++i) {
      int v = tid + i * 256;
      int r = v >> 2, kc = (v & 3) * 8;
      *(bf16x8*)((char*)&As[0][0] + r * 80 + kc * 2) =
          *(const bf16x8*)&A[(size_t)(brow + r) * K + k0 + kc];
      bf16x8 bv = {};
      if ((bcol + r) < N)
        bv = *(const bf16x8*)&Bt[(size_t)(bcol + r) * K + k0 + kc];
      *(bf16x8*)((char*)&Bs[0][0] + r * 80 + kc * 2) = bv;
    }
    __syncthreads();
    bf16x8 af[4], bfr[4];
#pragma unroll
    for (int m = 0; m < 4; ++m)
      af[m] = *(const bf16x8*)((const char*)&As[0][0] + (wm * 64 + m * 16 + l15) * 80 + lk * 16);
#pragma unroll
    for (int n = 0; n < 4; ++n)
      bfr[n] = *(const bf16x8*)((const char*)&Bs[0][0] + (wn * 64 + n * 16 + l15) * 80 + lk * 16);
#pragma unroll
    for (int m = 0; m < 4; ++m)
#pragma unroll
      for (int n = 0; n < 4; ++n)
        acc[m][n] = __builtin_amdgcn_mfma_f32_16x16x32_bf16(af[m], bfr[n], acc[m][n], 0, 0, 0);
    __syncthreads();
  }
  float* Pz = P + (size_t)blockIdx.z * M * N;
#pragma unroll
  for (int m = 0; m < 4; ++m) {
    int row = brow + wm * 64 + m * 16 + lk * 4;
#pragma unroll
    for (int n = 0; n < 4; ++n) {
      int col = bcol + wn * 64 + n * 16 + l15;
      if (col < N) {
#pragma unroll
        for (int r = 0; r < 4; ++r)
          Pz[(size_t)(row + r) * N + col] = acc[m][n][r];
      }
    }
  }
}

// ---------- reduce partials -> bcT (bf16x2 {B,C}, [n][tok]) + dtr[tok] ----------
__global__ __launch_bounds__(64) void reduce_bc(
    const float* __restrict__ P, unsigned int* __restrict__ bcT,
    float* __restrict__ dtr) {
  int tok = blockIdx.x;
  int n = threadIdx.x;
  const float* p0 = P + (size_t)tok * N_XP + n;
  float sB = 0.f, sC = 0.f;
#pragma unroll
  for (int z = 0; z < 16; ++z) {
    sB += p0[(size_t)z * N_TOK * N_XP];
    sC += p0[(size_t)z * N_TOK * N_XP + 64];
  }
  bcT[(size_t)n * N_TOK + tok] = (unsigned int)f2bf(sB) | ((unsigned int)f2bf(sC) << 16);
  if (n == 0) {
    float sd = 0.f;
    const float* pd = P + (size_t)tok * N_XP + 128;
#pragma unroll
    for (int z = 0; z < 16; ++z) sd += pd[(size_t)z * N_TOK * N_XP];
    dtr[tok] = sd;
  }
}

// ---------- causal depthwise conv (K=4) + SiLU ----------
__global__ __launch_bounds__(256) void conv_silu_kernel(
    const float* __restrict__ xz, const float* __restrict__ cw,
    const float* __restrict__ cb, float* __restrict__ xc,
    __hip_bfloat16* __restrict__ xcb) {
  int idx = blockIdx.x * 256 + threadIdx.x;
  int c = idx & (D_INNER - 1);
  int tok = idx >> 11;
  int l = tok & (SEQ_L - 1);
  float acc = cb[c];
#pragma unroll
  for (int k = 0; k < 4; ++k) {
    int ll = l - 3 + k;
    if (ll >= 0) acc = fmaf(xz[(size_t)(tok - 3 + k) * D_XZ + c], cw[c * 4 + k], acc);
  }
  float v = acc / (1.f + __expf(-acc));
  xc[idx] = v;
  xcb[idx] = __float2bfloat16(v);
}

// ---------- pack via LDS transpose: uaT[d][tok]={dt,dt*x}; ugT[d][tok]={Dx,g} ----------
__global__ __launch_bounds__(256) void pack_kernel(
    const float* __restrict__ xzf, const float* __restrict__ xc,
    const float* __restrict__ dtr, const float* __restrict__ dt_w,
    const float* __restrict__ dt_b, const float* __restrict__ Dv,
    float2* __restrict__ uaT, unsigned int* __restrict__ ugT) {
  __shared__ float2 la[64][33];
  __shared__ unsigned int lg[64][33];
  int tok0 = blockIdx.x * 32, d0 = blockIdx.y * 64;
  int t = threadIdx.x;
  int dl = t & 63, tc = t >> 6;
  int d = d0 + dl;
  float w = dt_w[d], bb = dt_b[d], Dd = Dv[d];
#pragma unroll
  for (int p = 0; p < 8; ++p) {
    int tl = p * 4 + tc;
    int tok = tok0 + tl;
    float xt = xc[(size_t)tok * D_INNER + d];
    float z = xzf[(size_t)tok * D_XZ + D_INNER + d];
    float dt = dtr[tok] * w + bb;
    dt = (dt > 20.f) ? dt : log1pf(__expf(dt));
    la[dl][tl] = make_float2(dt, dt * xt);
    float g = z / (1.f + __expf(-z));
    lg[dl][tl] = (unsigned int)f2bf(Dd * xt) | ((unsigned int)f2bf(g) << 16);
  }
  __syncthreads();
  int tl2 = t & 31, dg = t >> 5;
#pragma unroll
  for (int q = 0; q < 8; ++q) {
    int dl2 = q * 8 + dg;
    uaT[(size_t)(d0 + dl2) * N_TOK + tok0 + tl2] = la[dl2][tl2];
    ugT[(size_t)(d0 + dl2) * N_TOK + tok0 + tl2] = lg[dl2][tl2];
  }
}

// ---------- DPP wave-64 sum: result in lane 63, pure VALU ----------
template<int CTRL>
__device__ __forceinline__ float dppadd(float v) {
  int t = __builtin_amdgcn_update_dpp(0, __float_as_int(v), CTRL, 0xF, 0xF, true);
  return v + __int_as_float(t);
}
__device__ __forceinline__ float wave_sum64(float v) {
  v = dppadd<0x111>(v);  // row_shr:1
  v = dppadd<0x112>(v);  // row_shr:2
  v = dppadd<0x114>(v);  // row_shr:4
  v = dppadd<0x118>(v);  // row_shr:8
  v = dppadd<0x142>(v);  // row_bcast:15
  v = dppadd<0x143>(v);  // row_bcast:31
  return v;
}

// ---------- selective scan: wave per (b,d), lane=n; 2-deep pipeline ----------
#define TOK(dtv, dtxv, gv, bv, tt) { \
    float dA = __expf((dtv) * a); \
    s = fmaf(dA, s, (dtxv) * bf16lo(bv)); \
    float p = wave_sum64(s * bf16hi(bv)); \
    if (lane == 63) { \
      float yy = (p + bf16lo(gv)) * bf16hi(gv); \
      yo[(size_t)(tt) * D_INNER] = __float2bfloat16(yy); } }

#define COMPUTE(S, lb) \
  TOK(S##u0.x, S##u0.y, S##g0.x, S##b0.x, (lb) + 0) \
  TOK(S##u0.z, S##u0.w, S##g0.y, S##b0.y, (lb) + 1) \
  TOK(S##u1.x, S##u1.y, S##g0.z, S##b0.z, (lb) + 2) \
  TOK(S##u1.z, S##u1.w, S##g0.w, S##b0.w, (lb) + 3) \
  TOK(S##u2.x, S##u2.y, S##g1.x, S##b1.x, (lb) + 4) \
  TOK(S##u2.z, S##u2.w, S##g1.y, S##b1.y, (lb) + 5) \
  TOK(S##u3.x, S##u3.y, S##g1.z, S##b1.z, (lb) + 6) \
  TOK(S##u3.z, S##u3.w, S##g1.w, S##b1.w, (lb) + 7)

#define LOADBLK(S, lb) \
  S##u0 = ua[(lb) / 2]; S##u1 = ua[(lb) / 2 + 1]; \
  S##u2 = ua[(lb) / 2 + 2]; S##u3 = ua[(lb) / 2 + 3]; \
  S##g0 = ug[(lb) / 4]; S##g1 = ug[(lb) / 4 + 1]; \
  S##b0 = bc[(lb) / 4]; S##b1 = bc[(lb) / 4 + 1];

__global__ __launch_bounds__(256) void scan_kernel(
    const float2* __restrict__ uaT, const unsigned int* __restrict__ ugT,
    const unsigned int* __restrict__ bcT, const float* __restrict__ A_log,
    __hip_bfloat16* __restrict__ ybb, float* __restrict__ state_out) {
  int wid = (blockIdx.x * 256 + threadIdx.x) >> 6;
  int lane = threadIdx.x & 63;
  int b = wid >> 11, d = wid & (D_INNER - 1);
  float a = -__expf(A_log[d * D_STATE + lane]);
  float s = 0.f;
  const int tok0 = b * SEQ_L;
  const float4* ua = (const float4*)(uaT + (size_t)d * N_TOK + tok0);
  const uint4* ug = (const uint4*)(ugT + (size_t)d * N_TOK + tok0);
  const uint4* bc = (const uint4*)(bcT + (size_t)lane * N_TOK + tok0);
  __hip_bfloat16* yo = ybb + (size_t)tok0 * D_INNER + d;
  float4 Au0, Au1, Au2, Au3, Bu0, Bu1, Bu2, Bu3;
  uint4 Ag0, Ag1, Bg0, Bg1, Ab0, Ab1, Bb0, Bb1;
  LOADBLK(A, 0)
#pragma unroll 1
  for (int l = 0; l < SEQ_L; l += 16) {
    LOADBLK(B, l + 8)
    COMPUTE(A, l)
    if (l + 16 < SEQ_L) { LOADBLK(A, l + 16) }
    COMPUTE(B, l + 8)
  }
  state_out[(size_t)wid * D_STATE + lane] = s;
}

extern "C" void kernel_launch(void* const* d_in, const int* in_sizes, int n_in,
                              void* d_out, int out_size, void* d_ws, size_t ws_size,
                              hipStream_t stream) {
  const float* x         = (const float*)d_in[0];
  const float* in_proj_w = (const float*)d_in[1];
  const float* conv_w    = (const float*)d_in[2];
  const float* conv_b    = (const float*)d_in[3];
  const float* x_proj_w  = (const float*)d_in[4];
  const float* dt_w      = (const float*)d_in[5];
  const float* dt_b      = (const float*)d_in[6];
  const float* A_log     = (const float*)d_in[7];
  const float* Dvec      = (const float*)d_in[8];
  const float* out_proj_w= (const float*)d_in[9];

  char* w = (char*)d_ws;
  __hip_bfloat16* Wt1 = (__hip_bfloat16*)w; w += (size_t)D_XZ * D_MODEL * 2;      // 8 MB
  __hip_bfloat16* Wt2 = (__hip_bfloat16*)w; w += (size_t)N_XP * D_INNER * 2;      // 516 KB
  __hip_bfloat16* Wt3 = (__hip_bfloat16*)w; w += (size_t)D_MODEL * D_INNER * 2;   // 4 MB
  float*          xzf = (float*)w;          w += (size_t)N_TOK * D_XZ * 4;        // 16 MB
  float*          xc  = (float*)w;          w += (size_t)N_TOK * D_INNER * 4;     // 8 MB
  __hip_bfloat16* xcb = (__hip_bfloat16*)w; w += (size_t)N_TOK * D_INNER * 2;     // 4 MB
  float*          P   = (float*)w;          w += (size_t)16 * N_TOK * N_XP * 4;   // 8.45 MB
  unsigned int*   bcT = (unsigned int*)w;   w += (size_t)D_STATE * N_TOK * 4;     // 256 KB
  float*          dtr = (float*)w;          w += (size_t)N_TOK * 4;               // 4 KB
  float2*         uaT = (float2*)w;         w += (size_t)D_INNER * N_TOK * 8;     // 16 MB
  unsigned int*   ugT = (unsigned int*)w;   w += (size_t)D_INNER * N_TOK * 4;     // 8 MB
  __hip_bfloat16* ybb = (__hip_bfloat16*)w; w += (size_t)N_TOK * D_INNER * 2;     // 4 MB

  float* out       = (float*)d_out;
  float* state_out = out + (size_t)N_TOK * D_MODEL;

  dim3 blk(256);
  transpose_bf16<<<dim3(D_XZ / 64, D_MODEL / 64), blk, 0, stream>>>(in_proj_w, Wt1, D_MODEL, D_XZ);
  transpose_bf16<<<dim3((N_XP + 63) / 64, D_INNER / 64), blk, 0, stream>>>(x_proj_w, Wt2, D_INNER, N_XP);
  transpose_bf16<<<dim3(D_MODEL / 64, D_INNER / 64), blk, 0, stream>>>(out_proj_w, Wt3, D_INNER, D_MODEL);
  // 1) xz = x @ in_proj_w (A f32 converted in stage)
  gemm_bf16_tn<1><<<dim3(D_XZ / 128, N_TOK / 128), blk, 0, stream>>>(x, Wt1, xzf, N_TOK, D_XZ, D_MODEL);
  // 2) conv + silu
  conv_silu_kernel<<<(N_TOK * D_INNER) / 256, blk, 0, stream>>>(xzf, conv_w, conv_b, xc, xcb);
  // 3) xp partials: split-K x16
  gemm2_splitk<<<dim3((N_XP + 127) / 128, N_TOK / 128, 16), blk, 0, stream>>>(xcb, Wt2, P, N_TOK, N_XP, D_INNER);
  // 4) reduce -> bcT (bf16) + dtr
  reduce_bc<<<N_TOK, dim3(64), 0, stream>>>(P, bcT, dtr);
  // 5) pack transposed streams
  pack_kernel<<<dim3(N_TOK / 32, D_INNER / 64), blk, 0, stream>>>(xzf, xc, dtr, dt_w, dt_b, Dvec, uaT, ugT);
  // 6) scan
  scan_kernel<<<(2 * D_INNER * 64) / 256, blk, 0, stream>>>(uaT, ugT, bcT, A_log, ybb, state_out);
  // 7) out = y @ out_proj_w
  gemm_bf16_tn<0><<<dim3(D_MODEL / 128, N_TOK / 128), blk, 0, stream>>>(ybb, Wt3, out, N_TOK, D_MODEL, D_INNER);
}